// Round 1
// baseline (308.856 us; speedup 1.0000x reference)
//
#include <hip/hip_runtime.h>

// CrossNet fused kernel: out = initial * (X @ alphas) + X + bias
// B=16384 rows, D=2048 cols, fp32.
// One wave per row: dot-product + epilogue in a single pass so X is
// fetched from HBM exactly once. 402 MB total traffic -> ~64us floor.

#define CN_D 2048
#define CN_ROWS 16384

__global__ __launch_bounds__(256) void crossnet_kernel(
    const float* __restrict__ initial,
    const float* __restrict__ X,
    const float* __restrict__ alphas,
    const float* __restrict__ bias,
    float* __restrict__ out)
{
    const int wave = threadIdx.x >> 6;          // 0..3
    const int lane = threadIdx.x & 63;
    const int row  = (blockIdx.x << 2) + wave;  // 4 rows per block

    const float4* __restrict__ Xrow = (const float4*)(X       + (size_t)row * CN_D);
    const float4* __restrict__ Irow = (const float4*)(initial + (size_t)row * CN_D);
    const float4* __restrict__ A4   = (const float4*)alphas;   // (D,1) contiguous
    const float4* __restrict__ B4   = (const float4*)bias;
    float4*       __restrict__ Orow = (float4*)(out + (size_t)row * CN_D);

    // D/4 = 512 float4 per row; 64 lanes x 8 iters. Keep X in registers.
    float4 x[8];
    float acc = 0.0f;
#pragma unroll
    for (int k = 0; k < 8; ++k) {
        const int idx = (k << 6) + lane;        // coalesced: lane i -> chunk i
        x[k] = Xrow[idx];
        const float4 a = A4[idx];
        acc += x[k].x * a.x + x[k].y * a.y + x[k].z * a.z + x[k].w * a.w;
    }

    // 64-lane butterfly reduction, then broadcast lane 0.
#pragma unroll
    for (int off = 32; off > 0; off >>= 1)
        acc += __shfl_down(acc, off, 64);
    const float scale = __shfl(acc, 0, 64);

#pragma unroll
    for (int k = 0; k < 8; ++k) {
        const int idx = (k << 6) + lane;
        const float4 i4 = Irow[idx];
        const float4 b4 = B4[idx];
        float4 o;
        o.x = fmaf(i4.x, scale, x[k].x + b4.x);
        o.y = fmaf(i4.y, scale, x[k].y + b4.y);
        o.z = fmaf(i4.z, scale, x[k].z + b4.z);
        o.w = fmaf(i4.w, scale, x[k].w + b4.w);
        Orow[idx] = o;
    }
}

extern "C" void kernel_launch(void* const* d_in, const int* in_sizes, int n_in,
                              void* d_out, int out_size, void* d_ws, size_t ws_size,
                              hipStream_t stream) {
    const float* initial = (const float*)d_in[0];
    const float* X       = (const float*)d_in[1];
    const float* alphas  = (const float*)d_in[2];
    const float* bias    = (const float*)d_in[3];
    float* out = (float*)d_out;

    // 16384 rows / 4 rows per block = 4096 blocks of 256 threads.
    crossnet_kernel<<<CN_ROWS / 4, 256, 0, stream>>>(initial, X, alphas, bias, out);
}